// Round 8
// baseline (99.048 us; speedup 1.0000x reference)
//
#include <hip/hip_runtime.h>
#include <hip/hip_bf16.h>

// Problem constants (B,T,C,H) = (4, 2048, 1024, 64)
#define B_ 4
#define T_ 2048
#define C_ 1024
#define H_ 64
#define M_ (B_ * T_)   // 8192 rows

// Split-K attention geometry: q-tile = 16 rows, k-tile = 64 keys,
// chunk = 2 k-tiles = 128 keys.  nch(qt) = (qt>>3)+1 (constant over 8-qt
// groups g): units/batch = 8 * sum_{g=1..16} g = 4*g*(g+1) prefix -> 1088.
#define UPB 1088
#define NUNITS (UPB * B_)   // 4352

typedef __attribute__((ext_vector_type(8))) short short8v;  // 8 bf16 = 4 VGPRs
typedef __attribute__((ext_vector_type(4))) float f32x4;

static __device__ __forceinline__ short bf16_bits(float f) {
    return __builtin_bit_cast(short, __float2bfloat16(f));
}

// ---------------------------------------------------------------------------
// Kernel 0: transpose+convert weights.  W[c][h] fp32 -> wt[m][h][c] bf16.
// ---------------------------------------------------------------------------
__global__ __launch_bounds__(256) void w_transpose(
    const float* __restrict__ Wq,
    const float* __restrict__ Wk,
    const float* __restrict__ Wv,
    ushort* __restrict__ wt)
{
    const int idx = blockIdx.x * 256 + threadIdx.x;        // 0 .. 3*64*256-1
    const int m  = idx / (H_ * (C_ / 4));
    const int r  = idx % (H_ * (C_ / 4));
    const int h  = r / (C_ / 4);
    const int c0 = (r % (C_ / 4)) * 4;
    const float* W = (m == 0) ? Wq : (m == 1) ? Wk : Wv;
    ushort4 o;
    o.x = (ushort)bf16_bits(W[(size_t)(c0 + 0) * H_ + h]);
    o.y = (ushort)bf16_bits(W[(size_t)(c0 + 1) * H_ + h]);
    o.z = (ushort)bf16_bits(W[(size_t)(c0 + 2) * H_ + h]);
    o.w = (ushort)bf16_bits(W[(size_t)(c0 + 3) * H_ + h]);
    *reinterpret_cast<ushort4*>(&wt[((size_t)m * H_ + h) * C_ + c0]) = o;
}

// ---------------------------------------------------------------------------
// Kernel 1: fused QKV projection via bf16 MFMA, in-block split-K x4.
// Grid 512 x 1024 thr (16 waves): wave = (kslice ks = wid>>2, colgroup
// cg = wid&3).  Each wave: 16 rows x 16 cols x {q,k,v}, K range
// [ks*256, ks*256+256) = 8 MFMA k-steps.  Slices 1-3 write partial accs to
// LDS (row stride 68 floats -> max 2-way bank alias = free), slice 0
// reduces + runs the coalesced epilogue.  2 blocks/CU -> 8 waves/SIMD:
// TLP hides the global-load chains that ILP attempts could not (R6/R7).
// mfma_f32_16x16x32_bf16 mapping (verified):
//   A: row=lane&15, k=(lane>>4)*8+i   B: col=lane&15, k=(lane>>4)*8+i
//   D: col=lane&15, row=(lane>>4)*4+reg
// ---------------------------------------------------------------------------
__global__ __launch_bounds__(1024, 8) void qkv_mfma(
    const float* __restrict__ x,
    const ushort* __restrict__ wt,     // [3][H][C] bf16 bits
    ushort* __restrict__ qb,
    ushort* __restrict__ kb,
    ushort* __restrict__ vtp)
{
    __shared__ float part[3][3][16][68];   // [ks-1][mat][row][col pad 68] 38.25KB
    __shared__ ushort q_s[16][72];         // [t][h], padded
    __shared__ ushort k_s[16][72];
    __shared__ ushort v_s[64][24];         // [h][t], padded (transposed V tile)

    const int lane = threadIdx.x & 63;
    const int wid  = threadIdx.x >> 6;     // 0..15
    const int cg   = wid & 3;              // column group (16 cols)
    const int ks   = wid >> 2;             // K slice (256 wide)
    const int row0 = blockIdx.x * 16;
    const int col0 = cg * 16;
    const int l15  = lane & 15;
    const int kg   = lane >> 4;

    const float*  xp = x  + (size_t)(row0 + l15) * C_ + ks * 256 + kg * 8;
    const ushort* bq = wt + (size_t)(0 * H_ + col0 + l15) * C_ + ks * 256 + kg * 8;
    const ushort* bk = bq + (size_t)H_ * C_;
    const ushort* bv = bk + (size_t)H_ * C_;

    f32x4 accq = {0.f, 0.f, 0.f, 0.f};
    f32x4 acck = {0.f, 0.f, 0.f, 0.f};
    f32x4 accv = {0.f, 0.f, 0.f, 0.f};

    #pragma unroll
    for (int kk = 0; kk < 8; ++kk) {
        const f32x4 a0 = *reinterpret_cast<const f32x4*>(xp + kk * 32);
        const f32x4 a1 = *reinterpret_cast<const f32x4*>(xp + kk * 32 + 4);
        short8v af;
        af[0] = bf16_bits(a0[0]); af[1] = bf16_bits(a0[1]);
        af[2] = bf16_bits(a0[2]); af[3] = bf16_bits(a0[3]);
        af[4] = bf16_bits(a1[0]); af[5] = bf16_bits(a1[1]);
        af[6] = bf16_bits(a1[2]); af[7] = bf16_bits(a1[3]);

        const short8v fq = *reinterpret_cast<const short8v*>(bq + kk * 32);
        const short8v fk = *reinterpret_cast<const short8v*>(bk + kk * 32);
        const short8v fv = *reinterpret_cast<const short8v*>(bv + kk * 32);

        accq = __builtin_amdgcn_mfma_f32_16x16x32_bf16(af, fq, accq, 0, 0, 0);
        acck = __builtin_amdgcn_mfma_f32_16x16x32_bf16(af, fk, acck, 0, 0, 0);
        accv = __builtin_amdgcn_mfma_f32_16x16x32_bf16(af, fv, accv, 0, 0, 0);
    }

    // ---- cross-slice reduction through LDS ----
    if (ks > 0) {
        #pragma unroll
        for (int j = 0; j < 4; ++j) {
            part[ks - 1][0][kg * 4 + j][col0 + l15] = accq[j];
            part[ks - 1][1][kg * 4 + j][col0 + l15] = acck[j];
            part[ks - 1][2][kg * 4 + j][col0 + l15] = accv[j];
        }
    }
    __syncthreads();
    if (ks == 0) {
        #pragma unroll
        for (int j = 0; j < 4; ++j) {
            #pragma unroll
            for (int s = 0; s < 3; ++s) {
                accq[j] += part[s][0][kg * 4 + j][col0 + l15];
                acck[j] += part[s][1][kg * 4 + j][col0 + l15];
                accv[j] += part[s][2][kg * 4 + j][col0 + l15];
            }
        }
        const float qscale = 0.03125f;  // 1024^-0.5
        #pragma unroll
        for (int j = 0; j < 4; ++j) {
            const int tr = kg * 4 + j;             // row within 16-row tile
            q_s[tr][col0 + l15] = (ushort)bf16_bits(accq[j] * qscale);
            k_s[tr][col0 + l15] = (ushort)bf16_bits(acck[j]);
            v_s[col0 + l15][tr] = (ushort)bf16_bits(accv[j]);
        }
    }
    __syncthreads();

    // ---- coalesced stores (768 threads used) ----
    const int tid = threadIdx.x;
    if (tid < 256) {                    // qb: 16 rows x 16 ushort4 segs
        const int row = tid >> 4;
        const int seg = tid & 15;
        *reinterpret_cast<ushort4*>(&qb[(size_t)(row0 + row) * H_ + seg * 4]) =
            *reinterpret_cast<const ushort4*>(&q_s[row][seg * 4]);
    } else if (tid < 512) {             // kb
        const int t2  = tid - 256;
        const int row = t2 >> 4;
        const int seg = t2 & 15;
        *reinterpret_cast<ushort4*>(&kb[(size_t)(row0 + row) * H_ + seg * 4]) =
            *reinterpret_cast<const ushort4*>(&k_s[row][seg * 4]);
    } else if (tid < 768) {             // vtp: 64 h x 4 ushort4 segs
        const int t2  = tid - 512;
        const int h   = t2 >> 2;
        const int seg = t2 & 3;
        const int bb  = row0 >> 11;
        const int tt0 = row0 & (T_ - 1);
        *reinterpret_cast<ushort4*>(&vtp[((size_t)bb * H_ + h) * T_ + tt0 + seg * 4]) =
            *reinterpret_cast<const ushort4*>(&v_s[h][seg * 4]);
    }
}

// ---------------------------------------------------------------------------
// Kernel 2a: split-K causal flash attention partials via bf16 MFMA.
// Grid 1088 blocks x 256 thr (4 waves); wave = one unit (b, qt, chunk of
// 2 k-tiles).  Unit decode: g max with 4g(g+1) <= u; rr = (u-4g(g+1))/(g+1);
// chunk = remainder; qt = 8g + rr.  Chunk covers k-tiles
// [2*chunk, min(2*chunk+2, qt/4+1)).  4352 units -> ~17 waves/CU.
// ---------------------------------------------------------------------------
__global__ __launch_bounds__(256, 4) void attn_part(
    const ushort* __restrict__ qb,
    const ushort* __restrict__ kb,
    const ushort* __restrict__ vtp,
    float* __restrict__ pO,       // [NUNITS][16][64]
    float* __restrict__ pML)      // [NUNITS][32]  (m rows 0-15, l rows 16-31)
{
    __shared__ ushort p_lds[4][16][68];   // per-wave P tile

    const int wid  = threadIdx.x >> 6;
    const int lane = threadIdx.x & 63;
    const int l15  = lane & 15;
    const int g    = lane >> 4;

    const int unit = blockIdx.x * 4 + wid;
    const int b = unit / UPB;
    const int u = unit - b * UPB;
    int gg = 0;
    #pragma unroll
    for (int t = 1; t < 16; ++t)
        if (u >= 4 * t * (t + 1)) gg = t;
    const int u2    = u - 4 * gg * (gg + 1);
    const int rr    = u2 / (gg + 1);
    const int chunk = u2 - rr * (gg + 1);
    const int qt    = gg * 8 + rr;

    const int qrow0   = qt * 16;
    const int diag_kt = qt >> 2;
    const int kt_lo   = chunk * 2;
    const int kt_hi   = min(kt_lo + 2, diag_kt + 1);   // exclusive

    const ushort* kbase_b = kb  + (size_t)b * T_ * H_;
    const ushort* vbase_b = vtp + (size_t)b * H_ * T_;

    const ushort* qp = qb + ((size_t)(b * T_ + qrow0 + l15)) * H_ + g * 8;
    const short8v qf0 = *reinterpret_cast<const short8v*>(qp);
    const short8v qf1 = *reinterpret_cast<const short8v*>(qp + 32);

    f32x4 accO[4];
    float m[4], l[4];
    #pragma unroll
    for (int r = 0; r < 4; ++r) {
        accO[r] = (f32x4){0.f, 0.f, 0.f, 0.f};
        m[r] = -1e30f; l[r] = 0.f;
    }

    #pragma unroll 2
    for (int kt = kt_lo; kt < kt_hi; ++kt) {
        const int k0 = kt * 64;
        const bool mask = (kt == diag_kt);

        // ---- QK^T: S[16 q x 64 keys] as 4 col-tiles ----
        f32x4 s[4];
        #pragma unroll
        for (int c = 0; c < 4; ++c) s[c] = (f32x4){0.f, 0.f, 0.f, 0.f};
        const ushort* kbase = kbase_b + (size_t)k0 * H_;
        #pragma unroll
        for (int c = 0; c < 4; ++c) {
            const ushort* kp = kbase + (size_t)(c * 16 + l15) * H_ + g * 8;
            const short8v kf0 = *reinterpret_cast<const short8v*>(kp);
            const short8v kf1 = *reinterpret_cast<const short8v*>(kp + 32);
            s[c] = __builtin_amdgcn_mfma_f32_16x16x32_bf16(qf0, kf0, s[c], 0, 0, 0);
            s[c] = __builtin_amdgcn_mfma_f32_16x16x32_bf16(qf1, kf1, s[c], 0, 0, 0);
        }

        // ---- V fragment loads (independent of softmax; latency hidden) ----
        short8v vf0[4], vf1[4];
        #pragma unroll
        for (int ht = 0; ht < 4; ++ht) {
            const ushort* vp = vbase_b + (size_t)(ht * 16 + l15) * T_ + k0 + g * 8;
            vf0[ht] = *reinterpret_cast<const short8v*>(vp);
            vf1[ht] = *reinterpret_cast<const short8v*>(vp + 32);
        }

        // ---- causal mask (diagonal tile only) ----
        if (mask) {
            #pragma unroll
            for (int c = 0; c < 4; ++c) {
                const int key = k0 + c * 16 + l15;
                #pragma unroll
                for (int r = 0; r < 4; ++r) {
                    const int row = qrow0 + g * 4 + r;
                    if (key > row) s[c][r] = -1e30f;
                }
            }
        }

        // ---- online softmax: per-row reduce across 16 lanes ----
        float tm[4];
        #pragma unroll
        for (int r = 0; r < 4; ++r) {
            tm[r] = fmaxf(fmaxf(s[0][r], s[1][r]), fmaxf(s[2][r], s[3][r]));
            #pragma unroll
            for (int off = 1; off < 16; off <<= 1)
                tm[r] = fmaxf(tm[r], __shfl_xor(tm[r], off));
        }
        float corr[4];
        #pragma unroll
        for (int r = 0; r < 4; ++r) {
            const float mn = fmaxf(m[r], tm[r]);
            corr[r] = __expf(m[r] - mn);
            m[r] = mn;
        }
        #pragma unroll
        for (int ht = 0; ht < 4; ++ht)
            #pragma unroll
            for (int r = 0; r < 4; ++r)
                accO[ht][r] *= corr[r];

        float ts[4] = {0.f, 0.f, 0.f, 0.f};
        #pragma unroll
        for (int c = 0; c < 4; ++c) {
            #pragma unroll
            for (int r = 0; r < 4; ++r) {
                const float p = __expf(s[c][r] - m[r]);
                ts[r] += p;
                p_lds[wid][g * 4 + r][c * 16 + l15] = (ushort)bf16_bits(p);
            }
        }
        #pragma unroll
        for (int r = 0; r < 4; ++r) {
            #pragma unroll
            for (int off = 1; off < 16; off <<= 1)
                ts[r] += __shfl_xor(ts[r], off);
            l[r] = l[r] * corr[r] + ts[r];
        }

        // ---- PA fragments from per-wave LDS tile ----
        const short8v pa0 = *reinterpret_cast<const short8v*>(&p_lds[wid][l15][g * 8]);
        const short8v pa1 = *reinterpret_cast<const short8v*>(&p_lds[wid][l15][32 + g * 8]);

        // ---- PV: O += P x V ----
        #pragma unroll
        for (int ht = 0; ht < 4; ++ht) {
            accO[ht] = __builtin_amdgcn_mfma_f32_16x16x32_bf16(pa0, vf0[ht], accO[ht], 0, 0, 0);
            accO[ht] = __builtin_amdgcn_mfma_f32_16x16x32_bf16(pa1, vf1[ht], accO[ht], 0, 0, 0);
        }
    }

    // ---- partial store ----
    float* po = pO + (size_t)unit * (16 * 64);
    #pragma unroll
    for (int ht = 0; ht < 4; ++ht)
        #pragma unroll
        for (int r = 0; r < 4; ++r)
            po[(g * 4 + r) * 64 + ht * 16 + l15] = accO[ht][r];
    if (l15 == 0) {
        #pragma unroll
        for (int r = 0; r < 4; ++r) {
            pML[(size_t)unit * 32 + (g * 4 + r)]      = m[r];
            pML[(size_t)unit * 32 + 16 + (g * 4 + r)] = l[r];
        }
    }
}

// ---------------------------------------------------------------------------
// Kernel 2b: merge partials.  Grid 512 blocks (b = bid>>7, qt = bid&127),
// 256 thr.  nch = (qt>>3)+1 partials per q-tile (up to 16).
// ---------------------------------------------------------------------------
__global__ __launch_bounds__(256) void attn_merge(
    const float* __restrict__ pO,
    const float* __restrict__ pML,
    float* __restrict__ out)
{
    const int b  = blockIdx.x >> 7;
    const int qt = blockIdx.x & 127;
    const int gg = qt >> 3;
    const int rr = qt & 7;
    const int base = b * UPB + 4 * gg * (gg + 1) + rr * (gg + 1);
    const int nch  = gg + 1;

    const int h  = threadIdx.x & 63;
    const int r0 = threadIdx.x >> 6;      // 0..3

    #pragma unroll
    for (int i = 0; i < 4; ++i) {
        const int row = r0 * 4 + i;       // 0..15
        float M = -1e30f;
        for (int u = 0; u < nch; ++u)
            M = fmaxf(M, pML[(size_t)(base + u) * 32 + row]);
        float O = 0.f, L = 0.f;
        for (int u = 0; u < nch; ++u) {
            const float w = __expf(pML[(size_t)(base + u) * 32 + row] - M);
            O += w * pO[(size_t)(base + u) * (16 * 64) + row * 64 + h];
            L += w * pML[(size_t)(base + u) * 32 + 16 + row];
        }
        out[((size_t)(b * T_ + qt * 16 + row)) * H_ + h] = O / L;
    }
}

// ---------------------------------------------------------------------------
// Launch. Input order is setup_inputs() dict order: x, Wk, Wq, Wv.
// ws: qb 1MB | kb 1MB | vtp 1MB | wt 384KB | pO 17.8MB | pML 557KB (~21.8MB).
// ---------------------------------------------------------------------------
extern "C" void kernel_launch(void* const* d_in, const int* in_sizes, int n_in,
                              void* d_out, int out_size, void* d_ws, size_t ws_size,
                              hipStream_t stream)
{
    const float* x  = (const float*)d_in[0];
    const float* Wk = (const float*)d_in[1];
    const float* Wq = (const float*)d_in[2];
    const float* Wv = (const float*)d_in[3];
    float* out = (float*)d_out;

    ushort* qbp = (ushort*)d_ws;                    // [M][64]
    ushort* kbp = qbp + (size_t)M_ * H_;            // [M][64]
    ushort* vtp = kbp + (size_t)M_ * H_;            // [B][64][T]
    ushort* wt  = vtp + (size_t)B_ * H_ * T_;       // [3][64][1024]
    float*  pO  = (float*)(wt + (size_t)3 * H_ * C_);      // [NUNITS][16][64]
    float*  pML = pO + (size_t)NUNITS * 16 * 64;           // [NUNITS][32]

    w_transpose<<<dim3((3 * H_ * (C_ / 4)) / 256), dim3(256), 0, stream>>>(Wq, Wk, Wv, wt);
    qkv_mfma<<<dim3(M_ / 16), dim3(1024), 0, stream>>>(x, wt, qbp, kbp, vtp);
    attn_part<<<dim3(NUNITS / 4), dim3(256), 0, stream>>>(qbp, kbp, vtp, pO, pML);
    attn_merge<<<dim3(128 * B_), dim3(256), 0, stream>>>(pO, pML, out);
}

// Round 9
// 72.279 us; speedup vs baseline: 1.3704x; 1.3704x over previous
//
#include <hip/hip_runtime.h>
#include <hip/hip_bf16.h>

// Problem constants (B,T,C,H) = (4, 2048, 1024, 64)
#define B_ 4
#define T_ 2048
#define C_ 1024
#define H_ 64
#define M_ (B_ * T_)   // 8192 rows

// Split-K attention geometry (round-6 best): q-tile = 16 rows, k-tile = 64,
// chunk = 4 k-tiles = 256 keys.  nch(qt) = qt/16 + 1; units/batch = 576.
#define UPB 576
#define NUNITS (UPB * B_)   // 2304

typedef __attribute__((ext_vector_type(8))) short short8v;  // 8 bf16 = 4 VGPRs
typedef __attribute__((ext_vector_type(4))) float f32x4;

static __device__ __forceinline__ short bf16_bits(float f) {
    return __builtin_bit_cast(short, __float2bfloat16(f));
}

// ---------------------------------------------------------------------------
// Kernel 0: transpose+convert weights.  W[c][h] fp32 -> wt[m][h][c] bf16.
// wt is viewed by the GEMM as a single [192][1024] B^T matrix.
// ---------------------------------------------------------------------------
__global__ __launch_bounds__(256) void w_transpose(
    const float* __restrict__ Wq,
    const float* __restrict__ Wk,
    const float* __restrict__ Wv,
    ushort* __restrict__ wt)
{
    const int idx = blockIdx.x * 256 + threadIdx.x;        // 0 .. 3*64*256-1
    const int m  = idx / (H_ * (C_ / 4));
    const int r  = idx % (H_ * (C_ / 4));
    const int h  = r / (C_ / 4);
    const int c0 = (r % (C_ / 4)) * 4;
    const float* W = (m == 0) ? Wq : (m == 1) ? Wk : Wv;
    ushort4 o;
    o.x = (ushort)bf16_bits(W[(size_t)(c0 + 0) * H_ + h]);
    o.y = (ushort)bf16_bits(W[(size_t)(c0 + 1) * H_ + h]);
    o.z = (ushort)bf16_bits(W[(size_t)(c0 + 2) * H_ + h]);
    o.w = (ushort)bf16_bits(W[(size_t)(c0 + 3) * H_ + h]);
    *reinterpret_cast<ushort4*>(&wt[((size_t)m * H_ + h) * C_ + c0]) = o;
}

// ---------------------------------------------------------------------------
// Kernel 1: fused QKV projection as a canonical LDS-staged bf16 MFMA GEMM.
// C[8192 x 192] = x[8192 x 1024] * wt^T, wt = [192][1024] bf16 (B^T form).
// Grid 256 blocks x 512 thr (8 waves). BM=32, BN=192, BK=64.
// Staging (coalesced, dense lines):
//   A: 512 thr x f32x4 -> cvt -> ds_write_b64   (x rows in 256B runs)
//   B: 512 thr x 3 short8                        (wt rows in 128B runs)
// Fragments via ds_read_b128 from padded LDS ([.][72], 144B row stride).
// Wave (wm = wid>>2, wn = wid&3): rows wm*16..+16, cols wn*48..+48 (3 frags).
// This replaces the R4-R8 fragment-direct loads whose 16-scattered-line
// pattern pinned the kernel at 43us regardless of ILP/occupancy.
// mfma_f32_16x16x32_bf16 mapping (verified):
//   A: row=lane&15, k=(lane>>4)*8+i   B: col=lane&15, k=(lane>>4)*8+i
//   D: col=lane&15, row=(lane>>4)*4+reg
// ---------------------------------------------------------------------------
__global__ __launch_bounds__(512, 2) void qkv_mfma(
    const float* __restrict__ x,
    const ushort* __restrict__ wt,     // [192][1024] bf16 bits
    ushort* __restrict__ qb,
    ushort* __restrict__ kb,
    ushort* __restrict__ vtp)
{
    __shared__ ushort A_lds[32][72];    // bf16 x-tile, padded
    __shared__ ushort B_lds[192][72];   // bf16 w-tile, padded
    __shared__ ushort q_s[32][72];      // epilogue staging
    __shared__ ushort k_s[32][72];
    __shared__ ushort v_s[64][40];      // [h][t] transposed V tile (32 t)

    const int tid  = threadIdx.x;
    const int lane = tid & 63;
    const int wid  = tid >> 6;          // 0..7
    const int wm   = wid >> 2;          // 0..1  (16-row group)
    const int wn   = wid & 3;           // 0..3  (48-col group)
    const int l15  = lane & 15;
    const int kg   = lane >> 4;
    const int row0 = blockIdx.x * 32;

    // staging indices (loop-invariant)
    const int arow  = tid >> 4;             // 0..31
    const int acol4 = (tid & 15) * 4;       // 0..60 step 4
    const float* xsrc = x + (size_t)(row0 + arow) * C_ + acol4;

    f32x4 acc[3];
    #pragma unroll
    for (int f = 0; f < 3; ++f) acc[f] = (f32x4){0.f, 0.f, 0.f, 0.f};

    for (int kt = 0; kt < C_ / 64; ++kt) {
        const int k0 = kt * 64;
        __syncthreads();   // protect previous tile reads

        // ---- stage A: x[32][64] fp32 -> bf16 LDS (one f32x4 per thread) ----
        {
            const f32x4 a = *reinterpret_cast<const f32x4*>(xsrc + k0);
            ushort4 ab;
            ab.x = (ushort)bf16_bits(a[0]); ab.y = (ushort)bf16_bits(a[1]);
            ab.z = (ushort)bf16_bits(a[2]); ab.w = (ushort)bf16_bits(a[3]);
            *reinterpret_cast<ushort4*>(&A_lds[arow][acol4]) = ab;
        }
        // ---- stage B: wt[192][64] bf16 (three short8 per thread) ----
        #pragma unroll
        for (int j = 0; j < 3; ++j) {
            const int idx  = tid + j * 512;      // 0..1535
            const int brow = idx >> 3;           // 0..191
            const int bseg = idx & 7;            // 0..7 (16B chunks)
            *reinterpret_cast<short8v*>(&B_lds[brow][bseg * 8]) =
                *reinterpret_cast<const short8v*>(&wt[(size_t)brow * C_ + k0 + bseg * 8]);
        }
        __syncthreads();

        // ---- compute: 2 k-steps of 32, 3 MFMAs each ----
        #pragma unroll
        for (int ks = 0; ks < 2; ++ks) {
            const short8v af = *reinterpret_cast<const short8v*>(
                &A_lds[wm * 16 + l15][ks * 32 + kg * 8]);
            #pragma unroll
            for (int f = 0; f < 3; ++f) {
                const short8v bf = *reinterpret_cast<const short8v*>(
                    &B_lds[wn * 48 + f * 16 + l15][ks * 32 + kg * 8]);
                acc[f] = __builtin_amdgcn_mfma_f32_16x16x32_bf16(af, bf, acc[f], 0, 0, 0);
            }
        }
    }

    // ---- epilogue: scatter acc into LDS staging tiles ----
    __syncthreads();   // done with A_lds/B_lds reads? (reuse none; just order)
    const float qscale = 0.03125f;  // 1024^-0.5
    #pragma unroll
    for (int f = 0; f < 3; ++f) {
        const int gc  = wn * 48 + f * 16;        // wave-uniform frag base col
        const int mat = gc >> 6;                  // 0=q 1=k 2=v (uniform)
        const int h0  = gc & 63;
        #pragma unroll
        for (int j = 0; j < 4; ++j) {
            const int trow = wm * 16 + kg * 4 + j;   // 0..31
            if (mat == 0)      q_s[trow][h0 + l15] = (ushort)bf16_bits(acc[f][j] * qscale);
            else if (mat == 1) k_s[trow][h0 + l15] = (ushort)bf16_bits(acc[f][j]);
            else               v_s[h0 + l15][trow] = (ushort)bf16_bits(acc[f][j]);
        }
    }
    __syncthreads();

    // ---- coalesced stores ----
    {   // qb/kb: 32 rows x 16 ushort4 segs = 512 threads, one each
        const int row = tid >> 4;
        const int seg = tid & 15;
        const size_t o = (size_t)(row0 + row) * H_ + seg * 4;
        *reinterpret_cast<ushort4*>(&qb[o]) =
            *reinterpret_cast<const ushort4*>(&q_s[row][seg * 4]);
        *reinterpret_cast<ushort4*>(&kb[o]) =
            *reinterpret_cast<const ushort4*>(&k_s[row][seg * 4]);
    }
    {   // vtp: 64 h x 8 ushort4 segs (32 t) = 512 threads, one each
        const int h   = tid >> 3;
        const int seg = tid & 7;
        const int bb  = row0 >> 11;
        const int tt0 = row0 & (T_ - 1);
        *reinterpret_cast<ushort4*>(&vtp[((size_t)bb * H_ + h) * T_ + tt0 + seg * 4]) =
            *reinterpret_cast<const ushort4*>(&v_s[h][seg * 4]);
    }
}

// ---------------------------------------------------------------------------
// Kernel 2a: split-K causal flash attention partials (round-6 version).
// Grid 576 blocks x 256 thr (4 waves); wave = one unit (b, qt, chunk of 4
// k-tiles).  Decode: a max with 8a(a+1) <= u; rr = (u-8a(a+1))/(a+1);
// chunk = remainder; qt = 16a + rr.
// ---------------------------------------------------------------------------
__global__ __launch_bounds__(256) void attn_part(
    const ushort* __restrict__ qb,
    const ushort* __restrict__ kb,
    const ushort* __restrict__ vtp,
    float* __restrict__ pO,       // [NUNITS][16][64]
    float* __restrict__ pML)      // [NUNITS][32]  (m rows 0-15, l rows 16-31)
{
    __shared__ ushort p_lds[4][16][68];   // per-wave P tile

    const int wid  = threadIdx.x >> 6;
    const int lane = threadIdx.x & 63;
    const int l15  = lane & 15;
    const int g    = lane >> 4;

    const int unit = blockIdx.x * 4 + wid;
    const int b = unit / UPB;
    const int u = unit - b * UPB;
    int a = 0;
    #pragma unroll
    for (int t = 1; t < 8; ++t)
        if (u >= 8 * t * (t + 1)) a = t;
    const int u2    = u - 8 * a * (a + 1);
    const int rr    = u2 / (a + 1);
    const int chunk = u2 - rr * (a + 1);
    const int qt    = a * 16 + rr;

    const int qrow0   = qt * 16;
    const int diag_kt = qt >> 2;
    const int kt_lo   = chunk * 4;
    const int kt_hi   = min(kt_lo + 4, diag_kt + 1);   // exclusive

    const ushort* kbase_b = kb  + (size_t)b * T_ * H_;
    const ushort* vbase_b = vtp + (size_t)b * H_ * T_;

    const ushort* qp = qb + ((size_t)(b * T_ + qrow0 + l15)) * H_ + g * 8;
    const short8v qf0 = *reinterpret_cast<const short8v*>(qp);
    const short8v qf1 = *reinterpret_cast<const short8v*>(qp + 32);

    f32x4 accO[4];
    float m[4], l[4];
    #pragma unroll
    for (int r = 0; r < 4; ++r) {
        accO[r] = (f32x4){0.f, 0.f, 0.f, 0.f};
        m[r] = -1e30f; l[r] = 0.f;
    }

    auto do_tile = [&](int kt, bool mask) {
        const int k0 = kt * 64;

        // ---- QK^T: S[16 q x 64 keys] as 4 col-tiles ----
        f32x4 s[4];
        #pragma unroll
        for (int c = 0; c < 4; ++c) s[c] = (f32x4){0.f, 0.f, 0.f, 0.f};
        const ushort* kbase = kbase_b + (size_t)k0 * H_;
        #pragma unroll
        for (int c = 0; c < 4; ++c) {
            const ushort* kp = kbase + (size_t)(c * 16 + l15) * H_ + g * 8;
            const short8v kf0 = *reinterpret_cast<const short8v*>(kp);
            const short8v kf1 = *reinterpret_cast<const short8v*>(kp + 32);
            s[c] = __builtin_amdgcn_mfma_f32_16x16x32_bf16(qf0, kf0, s[c], 0, 0, 0);
            s[c] = __builtin_amdgcn_mfma_f32_16x16x32_bf16(qf1, kf1, s[c], 0, 0, 0);
        }

        // ---- V fragment loads (independent of softmax; latency hidden) ----
        short8v vf0[4], vf1[4];
        #pragma unroll
        for (int ht = 0; ht < 4; ++ht) {
            const ushort* vp = vbase_b + (size_t)(ht * 16 + l15) * T_ + k0 + g * 8;
            vf0[ht] = *reinterpret_cast<const short8v*>(vp);
            vf1[ht] = *reinterpret_cast<const short8v*>(vp + 32);
        }

        // ---- causal mask (diagonal tile only) ----
        if (mask) {
            #pragma unroll
            for (int c = 0; c < 4; ++c) {
                const int key = k0 + c * 16 + l15;
                #pragma unroll
                for (int r = 0; r < 4; ++r) {
                    const int row = qrow0 + g * 4 + r;
                    if (key > row) s[c][r] = -1e30f;
                }
            }
        }

        // ---- online softmax: per-row reduce across 16 lanes ----
        float tm[4];
        #pragma unroll
        for (int r = 0; r < 4; ++r) {
            tm[r] = fmaxf(fmaxf(s[0][r], s[1][r]), fmaxf(s[2][r], s[3][r]));
            #pragma unroll
            for (int off = 1; off < 16; off <<= 1)
                tm[r] = fmaxf(tm[r], __shfl_xor(tm[r], off));
        }
        float corr[4];
        #pragma unroll
        for (int r = 0; r < 4; ++r) {
            const float mn = fmaxf(m[r], tm[r]);
            corr[r] = __expf(m[r] - mn);
            m[r] = mn;
        }
        #pragma unroll
        for (int ht = 0; ht < 4; ++ht)
            #pragma unroll
            for (int r = 0; r < 4; ++r)
                accO[ht][r] *= corr[r];

        float ts[4] = {0.f, 0.f, 0.f, 0.f};
        #pragma unroll
        for (int c = 0; c < 4; ++c) {
            #pragma unroll
            for (int r = 0; r < 4; ++r) {
                const float p = __expf(s[c][r] - m[r]);
                ts[r] += p;
                p_lds[wid][g * 4 + r][c * 16 + l15] = (ushort)bf16_bits(p);
            }
        }
        #pragma unroll
        for (int r = 0; r < 4; ++r) {
            #pragma unroll
            for (int off = 1; off < 16; off <<= 1)
                ts[r] += __shfl_xor(ts[r], off);
            l[r] = l[r] * corr[r] + ts[r];
        }

        // ---- PA fragments from per-wave LDS tile ----
        const short8v pa0 = *reinterpret_cast<const short8v*>(&p_lds[wid][l15][g * 8]);
        const short8v pa1 = *reinterpret_cast<const short8v*>(&p_lds[wid][l15][32 + g * 8]);

        // ---- PV: O += P x V ----
        #pragma unroll
        for (int ht = 0; ht < 4; ++ht) {
            accO[ht] = __builtin_amdgcn_mfma_f32_16x16x32_bf16(pa0, vf0[ht], accO[ht], 0, 0, 0);
            accO[ht] = __builtin_amdgcn_mfma_f32_16x16x32_bf16(pa1, vf1[ht], accO[ht], 0, 0, 0);
        }
    };

    if (kt_hi == kt_lo + 4 && kt_hi <= diag_kt) {
        #pragma unroll
        for (int i = 0; i < 4; ++i) do_tile(kt_lo + i, false);
    } else {
        for (int kt = kt_lo; kt < kt_hi; ++kt) do_tile(kt, kt == diag_kt);
    }

    // ---- partial store ----
    float* po = pO + (size_t)unit * (16 * 64);
    #pragma unroll
    for (int ht = 0; ht < 4; ++ht)
        #pragma unroll
        for (int r = 0; r < 4; ++r)
            po[(g * 4 + r) * 64 + ht * 16 + l15] = accO[ht][r];
    if (l15 == 0) {
        #pragma unroll
        for (int r = 0; r < 4; ++r) {
            pML[(size_t)unit * 32 + (g * 4 + r)]      = m[r];
            pML[(size_t)unit * 32 + 16 + (g * 4 + r)] = l[r];
        }
    }
}

// ---------------------------------------------------------------------------
// Kernel 2b: merge partials (round-6 version).  Grid 512 blocks
// (b = bid>>7, qt = bid&127), 256 thr; nch = qt/16 + 1 (<= 8).
// ---------------------------------------------------------------------------
__global__ __launch_bounds__(256) void attn_merge(
    const float* __restrict__ pO,
    const float* __restrict__ pML,
    float* __restrict__ out)
{
    const int b  = blockIdx.x >> 7;
    const int qt = blockIdx.x & 127;
    const int a  = qt >> 4;
    const int rr = qt & 15;
    const int base = b * UPB + 8 * a * (a + 1) + rr * (a + 1);
    const int nch  = a + 1;

    const int h  = threadIdx.x & 63;
    const int r0 = threadIdx.x >> 6;      // 0..3

    #pragma unroll
    for (int i = 0; i < 4; ++i) {
        const int row = r0 * 4 + i;       // 0..15
        float M = -1e30f;
        for (int u = 0; u < nch; ++u)
            M = fmaxf(M, pML[(size_t)(base + u) * 32 + row]);
        float O = 0.f, L = 0.f;
        for (int u = 0; u < nch; ++u) {
            const float w = __expf(pML[(size_t)(base + u) * 32 + row] - M);
            O += w * pO[(size_t)(base + u) * (16 * 64) + row * 64 + h];
            L += w * pML[(size_t)(base + u) * 32 + 16 + row];
        }
        out[((size_t)(b * T_ + qt * 16 + row)) * H_ + h] = O / L;
    }
}

// ---------------------------------------------------------------------------
// Launch. Input order is setup_inputs() dict order: x, Wk, Wq, Wv.
// ws: qb 1MB | kb 1MB | vtp 1MB | wt 384KB | pO 9.4MB | pML 294KB (~13.1MB).
// ---------------------------------------------------------------------------
extern "C" void kernel_launch(void* const* d_in, const int* in_sizes, int n_in,
                              void* d_out, int out_size, void* d_ws, size_t ws_size,
                              hipStream_t stream)
{
    const float* x  = (const float*)d_in[0];
    const float* Wk = (const float*)d_in[1];
    const float* Wq = (const float*)d_in[2];
    const float* Wv = (const float*)d_in[3];
    float* out = (float*)d_out;

    ushort* qbp = (ushort*)d_ws;                    // [M][64]
    ushort* kbp = qbp + (size_t)M_ * H_;            // [M][64]
    ushort* vtp = kbp + (size_t)M_ * H_;            // [B][64][T]
    ushort* wt  = vtp + (size_t)B_ * H_ * T_;       // [192][1024]
    float*  pO  = (float*)(wt + (size_t)3 * H_ * C_);      // [NUNITS][16][64]
    float*  pML = pO + (size_t)NUNITS * 16 * 64;           // [NUNITS][32]

    w_transpose<<<dim3((3 * H_ * (C_ / 4)) / 256), dim3(256), 0, stream>>>(Wq, Wk, Wv, wt);
    qkv_mfma<<<dim3(M_ / 32), dim3(512), 0, stream>>>(x, wt, qbp, kbp, vtp);
    attn_part<<<dim3(NUNITS / 4), dim3(256), 0, stream>>>(qbp, kbp, vtp, pO, pML);
    attn_merge<<<dim3(128 * B_), dim3(256), 0, stream>>>(pO, pML, out);
}